// Round 3
// baseline (9225.900 us; speedup 1.0000x reference)
//
#include <hip/hip_runtime.h>
#include <math.h>

#define NN 1296          // 36*36 nodes
#define LROWS 39         // dwords per band row in Lg: 37 band slots + c_k + rsv
#define LGROWS (NN + 96)
#define LGSTRIDE (LGROWS * LROWS)   // 54288 dwords per system
#define VWAIT() asm volatile("s_waitcnt vmcnt(0)" ::: "memory")

// ---------------- 3x3 SAME conv, NCHW/OIHW, co-tile of 8 per thread ----------
__global__ __launch_bounds__(256) void conv3x3_k(
    const float* __restrict__ in, const float* __restrict__ wgt,
    const float* __restrict__ bias, float* __restrict__ out,
    int Cin, int Cout, int relu)
{
  const int b  = blockIdx.z;
  const int co0 = blockIdx.y * 8;
  const int p  = blockIdx.x * 256 + threadIdx.x;
  if (p >= NN) return;
  const int py = p / 36, px = p % 36;
  float acc[8];
#pragma unroll
  for (int t = 0; t < 8; ++t) acc[t] = (co0 + t < Cout) ? bias[co0 + t] : 0.f;
  for (int ci = 0; ci < Cin; ++ci) {
    const float* __restrict__ inp = in + (size_t)(b * Cin + ci) * NN;
#pragma unroll
    for (int dy = 0; dy < 3; ++dy) {
      const int yy = py + dy - 1;
#pragma unroll
      for (int dx = 0; dx < 3; ++dx) {
        const int xx = px + dx - 1;
        const float v = ((unsigned)yy < 36u && (unsigned)xx < 36u) ? inp[yy * 36 + xx] : 0.f;
#pragma unroll
        for (int t = 0; t < 8; ++t) {
          const float w = (co0 + t < Cout)
              ? wgt[(((co0 + t) * Cin + ci) * 3 + dy) * 3 + dx] : 0.f;
          acc[t] = fmaf(v, w, acc[t]);
        }
      }
    }
  }
#pragma unroll
  for (int t = 0; t < 8; ++t) {
    if (co0 + t < Cout) {
      float r = acc[t];
      if (relu) r = fmaxf(r, 0.f);
      out[(size_t)(b * Cout + co0 + t) * NN + p] = r;
    }
  }
}

// ------------- per-node edge weights: wh (to x+1), wv (to y+1) ---------------
__global__ __launch_bounds__(256) void edgew_k(const float* __restrict__ feat,
    float* __restrict__ wh, float* __restrict__ wv)
{
  const int b = blockIdx.y;
  const int n = blockIdx.x * 256 + threadIdx.x;
  if (n >= NN) return;
  const int col = n % 36, row = n / 36;
  float sh = 0.f, sv = 0.f;
#pragma unroll
  for (int f = 0; f < 6; ++f) {
    const float* __restrict__ fp = feat + (size_t)(b * 6 + f) * NN;
    const float a = fp[n];
    if (col < 35) { const float d = a - fp[n + 1];  sh += d * d; }
    if (row < 35) { const float d = a - fp[n + 36]; sv += d * d; }
  }
  wh[b * NN + n] = (col < 35) ? expf(-sh * 1e4f) : 0.f;
  wv[b * NN + n] = (row < 35) ? expf(-sv * 1e4f) : 0.f;
}

// ---- 9x { build banded A, register-resident Cholesky + fused fwd, back-sub }
// One wave per (b,c) system. Lane d owns band diagonal d (d=37 = RHS row).
// Active 37-column window lives in registers W[37]; k-loop unrolled by 37 so
// the circular index (p+j)%37 is compile-time.
__global__ __launch_bounds__(64) void gtv_k(
    const float* __restrict__ xf, const float* __restrict__ up,
    const float* __restrict__ whg, const float* __restrict__ wvg,
    float* __restrict__ Lg, float* __restrict__ out)
{
  const int sys = blockIdx.x, b = sys / 3, ch = sys % 3;
  const int lane = threadIdx.x;

  __shared__ float4 ndL[1376];        // {diag, ah, av, y} per node (+zero pad)
  __shared__ float  ahL[36 + NN];     // front pad 36 zeros
  __shared__ float  avL[36 + NN];
  __shared__ float  csL[160];         // [0..36] cs, [37..99] zeros, [100..126] dump
  __shared__ float  ysL[NN + 40];     // current y (+zero tail pad)

  float u = up[0]; u = fminf(fmaxf(u, 0.001f), 1.0f);

  const float sel0  = (lane == 0)  ? 1.f : 0.f;
  const float sel1  = (lane == 1)  ? 1.f : 0.f;
  const float sel36 = (lane == 36) ? 1.f : 0.f;
  const float sel37 = (lane == 37) ? 1.f : 0.f;

  const int csAddr = (lane <= 36) ? lane : (63 + lane);   // dump at [100..126]
  const int gincr  = (lane <= 38) ? 156 : 0;              // bytes per step
  int gvoff0;
  if (lane <= 36)      gvoff0 = 152 * lane + 144;         // ((k+d)*39 + 36-d)*4 @k=0
  else if (lane == 37) gvoff0 = 148;                      // c_k slot
  else if (lane == 38) gvoff0 = 152;                      // rsv slot
  else                 gvoff0 = (LGSTRIDE - 64 + lane) * 4;  // static dump

  // one-time LDS init
  for (int t = lane; t < 160; t += 64) csL[t] = 0.f;
  if (lane < 36) { ahL[lane] = 0.f; avL[lane] = 0.f; }
  for (int t = NN + lane; t < NN + 40; t += 64) ysL[t] = 0.f;
  for (int t = NN + lane; t < 1376; t += 64) ndL[t] = make_float4(0.f, 0.f, 0.f, 0.f);
  for (int n = lane; n < NN; n += 64) ysL[n] = xf[(size_t)(b * 3 + ch) * NN + n];

  const float* __restrict__ whB = whg + b * NN;
  const float* __restrict__ wvB = wvg + b * NN;
  float* __restrict__ LsB = Lg + (size_t)sys * LGSTRIDE;

  for (int it = 0; it < 9; ++it) {
    // ---- phase 1: u-scaled reweighted edge coefficients ----
    for (int n = lane; n < NN; n += 64) {
      const float yn = ysL[n];
      const float zh = fmaxf(fabsf(yn - ysL[n + 1]),  0.01f);
      const float zv = fmaxf(fabsf(yn - ysL[n + 36]), 0.01f);
      ahL[36 + n] = u * whB[n] / zh;
      avL[36 + n] = u * wvB[n] / zv;
    }
    // ---- phase 2: packed per-node column data {diag, ah, av, y} ----
    for (int n = lane; n < NN; n += 64)
      ndL[n] = make_float4(1.f + ahL[35 + n] + ahL[36 + n] + avL[n] + avL[36 + n],
                           ahL[36 + n], avL[36 + n], ysL[n]);

    // ---- window prologue: columns 0..36 ----
    float W[37];
#pragma unroll
    for (int c = 0; c < 37; ++c) {
      const float4 nd = ndL[c];
      W[c] = fmaf(sel0, nd.x, fmaf(sel1, -nd.y, fmaf(sel36, -nd.z, sel37 * nd.w)));
    }

    // ---- phase 3: banded Cholesky, register window, fused forward sub ----
    int voff = gvoff0;
    for (int chunk = 0; chunk < 36; ++chunk) {     // 36*37 = 1332 uniform steps
      const int kb = chunk * 37;
#pragma unroll
      for (int p = 0; p < 37; ++p) {
        const float dpiv = __int_as_float(
            __builtin_amdgcn_readfirstlane(__float_as_int(W[p])));
        const float rsf = rsqrtf(fmaxf(dpiv, 1.0f));   // pivots >= 1; guards overrun steps
        const float cs  = W[p] * rsf;                  // lane37 = c_k
        const float srhs = __int_as_float(
            __builtin_amdgcn_readlane(__float_as_int(cs), 37));
        csL[csAddr] = cs;                              // lanes 37+ go to dump
        const float gval = (lane == 38) ? rsf : cs;    // lane37 stores c_k, 38 rsv
        *(float*)((char*)LsB + voff) = gval;           // fire-and-forget band row store
        voff += gincr;
        // trailing rank-1 update (+RHS row via sel37 fold), all in registers
#pragma unroll
        for (int j = 1; j <= 36; ++j) {
          const float a = csL[lane + j];               // pairs merge to ds_read2_b32
          const float q = csL[j];                      // broadcast read
          const float ae = fmaf(sel37, srhs, a);
          W[(p + j) % 37] = fmaf(-ae, q, W[(p + j) % 37]);
        }
        // insert fresh column k+37 into the freed slot
        const float4 nd = ndL[kb + p + 37];
        W[p] = fmaf(sel0, nd.x, fmaf(sel1, -nd.y, fmaf(sel36, -nd.z, sel37 * nd.w)));
      }
    }

    // ---- phase 4: back substitution (L^T x = c), register-chunked ----
    VWAIT();                                           // band-row stores -> loads
    float xcur[36];
#pragma unroll
    for (int m = 0; m < 36; ++m) xcur[m] = 0.f;
    for (int cb = 35; cb >= 0; --cb) {
      const int base = cb * 36;
      float raw[71];                                   // raw[i-1]@lane l = L[base+i][base+l]
#pragma unroll
      for (int i = 1; i <= 71; ++i)
        raw[i - 1] = LsB[(base + i) * LROWS + (36 - i) + lane];
      float w = LsB[(base + lane) * LROWS + 37];       // c_k
      const float rsB = LsB[(base + lane) * LROWS + 38];
#pragma unroll
      for (int m = 0; m < 36; ++m) {                   // coupling to solved block below
        const float Lv = (lane >= m) ? raw[35 + m] : 0.f;
        w -= Lv * xcur[m];
      }
      float myx = 0.f;
#pragma unroll
      for (int r = 35; r >= 0; --r) {
        const float t = w * rsB;
        const float xr = __int_as_float(
            __builtin_amdgcn_readlane(__float_as_int(t), r));
        myx = (lane == r) ? t : myx;
        if (r > 0) {
          const float Lv = (lane < r) ? raw[r - 1] : 0.f;
          w -= Lv * xr;
        }
        xcur[r] = xr;
      }
      if (lane < 36) ysL[base + lane] = myx;           // x becomes next iteration's y
    }
  }

  for (int n = lane; n < NN; n += 64) out[(size_t)(b * 3 + ch) * NN + n] = ysL[n];
}

// ----------------------------------------------------------------------------
extern "C" void kernel_launch(void* const* d_in, const int* in_sizes, int n_in,
                              void* d_out, int out_size, void* d_ws, size_t ws_size,
                              hipStream_t stream) {
  const float* xf     = (const float*)d_in[0];   // [2,3,36,36]
  const float* up     = (const float*)d_in[1];   // [1]
  const float* cw_in  = (const float*)d_in[3];   // [32,3,3,3]
  const float* b_in   = (const float*)d_in[4];   // [32]
  const float* cw_mid = (const float*)d_in[5];   // [5,32,32,3,3]
  const float* b_mid  = (const float*)d_in[6];   // [5,32]
  const float* cw_out = (const float*)d_in[7];   // [6,32,3,3]
  const float* b_out  = (const float*)d_in[8];   // [6]

  float* ws   = (float*)d_ws;
  float* wh   = ws;                   // 2592
  float* wv   = ws + 2592;            // 2592
  float* un   = ws + 5184;            // union region
  float* hb0  = un;                   // conv phase: 82944
  float* hb1  = un + 82944;           // 82944
  float* feat = un + 165888;          // 15552
  float* Lg   = un;                   // gtv phase: 6*54288 = 325728 (reuses conv bufs)

  const dim3 cgrid(6, 4, 2), cblk(256);
  conv3x3_k<<<cgrid, cblk, 0, stream>>>(xf, cw_in, b_in, hb0, 3, 32, 1);
  const float* src = hb0; float* dst = hb1;
  for (int i = 0; i < 5; ++i) {
    conv3x3_k<<<cgrid, cblk, 0, stream>>>(src, cw_mid + i * 9216, b_mid + i * 32,
                                          dst, 32, 32, 1);
    const float* t = dst; dst = (float*)src; src = t;
  }
  conv3x3_k<<<dim3(6, 1, 2), cblk, 0, stream>>>(src, cw_out, b_out, feat, 32, 6, 0);

  edgew_k<<<dim3(6, 2), cblk, 0, stream>>>(feat, wh, wv);

  gtv_k<<<dim3(6), dim3(64), 0, stream>>>(xf, up, wh, wv, Lg, (float*)d_out);
}

// Round 4
// 1139.040 us; speedup vs baseline: 8.0997x; 8.0997x over previous
//
#include <hip/hip_runtime.h>
#include <math.h>

#define NN 1296              // 36*36 nodes
#define OFF 40               // front pad (>=36, zeroed)
#define TOT (OFF + NN + 40)  // 1376 floats per node-array
#define KCH 240              // Chebyshev iterations per solve

// ---------------- 3x3 SAME conv, NCHW/OIHW, co-tile of 8 per thread ----------
__global__ __launch_bounds__(256) void conv3x3_k(
    const float* __restrict__ in, const float* __restrict__ wgt,
    const float* __restrict__ bias, float* __restrict__ out,
    int Cin, int Cout, int relu)
{
  const int b  = blockIdx.z;
  const int co0 = blockIdx.y * 8;
  const int p  = blockIdx.x * 256 + threadIdx.x;
  if (p >= NN) return;
  const int py = p / 36, px = p % 36;
  float acc[8];
#pragma unroll
  for (int t = 0; t < 8; ++t) acc[t] = (co0 + t < Cout) ? bias[co0 + t] : 0.f;
  for (int ci = 0; ci < Cin; ++ci) {
    const float* __restrict__ inp = in + (size_t)(b * Cin + ci) * NN;
#pragma unroll
    for (int dy = 0; dy < 3; ++dy) {
      const int yy = py + dy - 1;
#pragma unroll
      for (int dx = 0; dx < 3; ++dx) {
        const int xx = px + dx - 1;
        const float v = ((unsigned)yy < 36u && (unsigned)xx < 36u) ? inp[yy * 36 + xx] : 0.f;
#pragma unroll
        for (int t = 0; t < 8; ++t) {
          const float w = (co0 + t < Cout)
              ? wgt[(((co0 + t) * Cin + ci) * 3 + dy) * 3 + dx] : 0.f;
          acc[t] = fmaf(v, w, acc[t]);
        }
      }
    }
  }
#pragma unroll
  for (int t = 0; t < 8; ++t) {
    if (co0 + t < Cout) {
      float r = acc[t];
      if (relu) r = fmaxf(r, 0.f);
      out[(size_t)(b * Cout + co0 + t) * NN + p] = r;
    }
  }
}

// ------------- per-node edge weights: wh (to x+1), wv (to y+1) ---------------
__global__ __launch_bounds__(256) void edgew_k(const float* __restrict__ feat,
    float* __restrict__ wh, float* __restrict__ wv)
{
  const int b = blockIdx.y;
  const int n = blockIdx.x * 256 + threadIdx.x;
  if (n >= NN) return;
  const int col = n % 36, row = n / 36;
  float sh = 0.f, sv = 0.f;
#pragma unroll
  for (int f = 0; f < 6; ++f) {
    const float* __restrict__ fp = feat + (size_t)(b * 6 + f) * NN;
    const float a = fp[n];
    if (col < 35) { const float d = a - fp[n + 1];  sh += d * d; }
    if (row < 35) { const float d = a - fp[n + 36]; sv += d * d; }
  }
  wh[b * NN + n] = (col < 35) ? expf(-sh * 1e4f) : 0.f;
  wv[b * NN + n] = (row < 35) ? expf(-sv * 1e4f) : 0.f;
}

// ---- 9x { reweight -> Chebyshev semi-iteration solve of (I+uL)x = y } -------
// One block (512 threads) per (b,c) system. A is SPD, lambda in [1, 1+2*maxoff]
// (Gershgorin); Chebyshev 3-term recurrence, one 5-pt stencil + 1 barrier/iter.
__global__ __launch_bounds__(512) void gtv_cheb_k(
    const float* __restrict__ xf, const float* __restrict__ up,
    const float* __restrict__ whg, const float* __restrict__ wvg,
    float* __restrict__ out)
{
  const int sys = blockIdx.x, b = sys / 3, ch = sys % 3;
  const int tid = threadIdx.x;
  const int wave = tid >> 6, lane = tid & 63;

  __shared__ float ysL[TOT], ahL[TOT], avL[TOT], dA[TOT], dB[TOT];
  __shared__ float red[12];

  const int n0 = tid, n1 = tid + 512, n2 = tid + 1024;
  const bool a2 = (n2 < NN);                 // tid < 272
  const int nc[3] = { n0, n1, a2 ? n2 : 0 }; // clamped for safe reads
  const int nw[3] = { n0, n1, n2 };

  float u = up[0]; u = fminf(fmaxf(u, 0.001f), 1.0f);

  for (int t = tid; t < TOT; t += 512) {
    ysL[t] = 0.f; ahL[t] = 0.f; avL[t] = 0.f; dA[t] = 0.f; dB[t] = 0.f;
  }
  __syncthreads();

  const float* __restrict__ xfB = xf + (size_t)(b * 3 + ch) * NN;
  ysL[OFF + n0] = xfB[n0];
  ysL[OFF + n1] = xfB[n1];
  if (a2) ysL[OFF + n2] = xfB[n2];

  float wh[3], wv[3];
  wh[0] = whg[b * NN + n0]; wv[0] = wvg[b * NN + n0];
  wh[1] = whg[b * NN + n1]; wv[1] = wvg[b * NN + n1];
  wh[2] = a2 ? whg[b * NN + n2] : 0.f;
  wv[2] = a2 ? wvg[b * NN + n2] : 0.f;
  __syncthreads();

  float x[3] = {0.f, 0.f, 0.f};

  for (int it = 0; it < 9; ++it) {
    // ---- P1: u-scaled reweighted edge coefficients from current y ----
#pragma unroll
    for (int s = 0; s < 3; ++s) {
      const int i = OFF + nc[s];
      const float yn = ysL[i];
      const float ah = u * wh[s] / fmaxf(fabsf(yn - ysL[i + 1]),  0.01f);
      const float av = u * wv[s] / fmaxf(fabsf(yn - ysL[i + 36]), 0.01f);
      if (s < 2 || a2) { ahL[i] = ah; avL[i] = av; }
    }
    __syncthreads();

    // ---- P2: per-node stencil coeffs (regs), b -> dA, Gershgorin reduce ----
    float cL[3], cR[3], cU[3], cD[3], cc[3], bn[3];
    float mo = 0.f;
#pragma unroll
    for (int s = 0; s < 3; ++s) {
      const int i = OFF + nc[s];
      cL[s] = ahL[i - 1]; cR[s] = ahL[i]; cU[s] = avL[i - 36]; cD[s] = avL[i];
      const float offs = cL[s] + cR[s] + cU[s] + cD[s];
      cc[s] = 1.f + offs;
      bn[s] = ysL[i];
      if (s < 2 || a2) { dA[i] = bn[s]; mo = fmaxf(mo, offs); }
    }
#pragma unroll
    for (int o = 32; o >= 1; o >>= 1) mo = fmaxf(mo, __shfl_xor(mo, o));
    if (lane == 0) red[wave] = mo;
    __syncthreads();
    if (tid == 0) {
      float m = red[0];
      for (int w = 1; w < 8; ++w) m = fmaxf(m, red[w]);
      red[8] = m;
    }
    __syncthreads();

    const float maxoff = red[8];
    const float theta = 1.f + maxoff;           // (lmax+lmin)/2, lmin=1
    const float del   = fmaxf(maxoff, 1e-30f);  // (lmax-lmin)/2, guarded
    const float sig1  = theta / del;
    float rho = del / theta;

    // ---- P3: x0 = b, r0 = b - A b, d0 = r0/theta -> dB ----
    float r[3];
#pragma unroll
    for (int s = 0; s < 3; ++s) {
      const int i = OFF + nc[s];
      const float Ab = cc[s] * bn[s] - cL[s] * dA[i - 1] - cR[s] * dA[i + 1]
                     - cU[s] * dA[i - 36] - cD[s] * dA[i + 36];
      x[s] = bn[s];
      r[s] = bn[s] - Ab;
      if (s < 2 || a2) dB[i] = r[s] / theta;
    }
    __syncthreads();

    // ---- P4: Chebyshev 3-term recurrence (Saad Alg 12.1) ----
    float* dc = dB; float* dnx = dA;
    for (int k = 0; k < KCH; ++k) {
      float dv[3], Ad[3];
#pragma unroll
      for (int s = 0; s < 3; ++s) {
        const int i = OFF + nc[s];
        const float dn_ = dc[i];
        Ad[s] = cc[s] * dn_ - cL[s] * dc[i - 1] - cR[s] * dc[i + 1]
              - cU[s] * dc[i - 36] - cD[s] * dc[i + 36];
        dv[s] = dn_;
      }
      const float rn = 1.f / (2.f * sig1 - rho);
      const float cd = rn * rho, cr = 2.f * rn / del;
      rho = rn;
#pragma unroll
      for (int s = 0; s < 3; ++s) {
        x[s] += dv[s];
        r[s] -= Ad[s];
        if (s < 2 || a2) dnx[OFF + nw[s]] = cd * dv[s] + cr * r[s];
      }
      __syncthreads();
      float* t = dc; dc = dnx; dnx = t;
    }

    // ---- commit x as next iteration's y ----
#pragma unroll
    for (int s = 0; s < 3; ++s)
      if (s < 2 || a2) ysL[OFF + nw[s]] = x[s];
    __syncthreads();
  }

  float* __restrict__ outB = out + (size_t)(b * 3 + ch) * NN;
  outB[n0] = x[0];
  outB[n1] = x[1];
  if (a2) outB[n2] = x[2];
}

// ----------------------------------------------------------------------------
extern "C" void kernel_launch(void* const* d_in, const int* in_sizes, int n_in,
                              void* d_out, int out_size, void* d_ws, size_t ws_size,
                              hipStream_t stream) {
  const float* xf     = (const float*)d_in[0];   // [2,3,36,36]
  const float* up     = (const float*)d_in[1];   // [1]
  const float* cw_in  = (const float*)d_in[3];   // [32,3,3,3]
  const float* b_in   = (const float*)d_in[4];   // [32]
  const float* cw_mid = (const float*)d_in[5];   // [5,32,32,3,3]
  const float* b_mid  = (const float*)d_in[6];   // [5,32]
  const float* cw_out = (const float*)d_in[7];   // [6,32,3,3]
  const float* b_out  = (const float*)d_in[8];   // [6]

  float* ws   = (float*)d_ws;
  float* wh   = ws;                   // 2592
  float* wv   = ws + 2592;            // 2592
  float* hb0  = ws + 5184;            // 82944
  float* hb1  = hb0 + 82944;          // 82944
  float* feat = hb1 + 82944;          // 15552

  const dim3 cgrid(6, 4, 2), cblk(256);
  conv3x3_k<<<cgrid, cblk, 0, stream>>>(xf, cw_in, b_in, hb0, 3, 32, 1);
  const float* src = hb0; float* dst = hb1;
  for (int i = 0; i < 5; ++i) {
    conv3x3_k<<<cgrid, cblk, 0, stream>>>(src, cw_mid + i * 9216, b_mid + i * 32,
                                          dst, 32, 32, 1);
    const float* t = dst; dst = (float*)src; src = t;
  }
  conv3x3_k<<<dim3(6, 1, 2), cblk, 0, stream>>>(src, cw_out, b_out, feat, 32, 6, 0);

  edgew_k<<<dim3(6, 2), cblk, 0, stream>>>(feat, wh, wv);

  gtv_cheb_k<<<dim3(6), dim3(512), 0, stream>>>(xf, up, wh, wv, (float*)d_out);
}

// Round 5
// 248.481 us; speedup vs baseline: 37.1292x; 4.5840x over previous
//
#include <hip/hip_runtime.h>
#include <math.h>

#define NN 1296              // 36*36 nodes
#define OFF 40               // front pad (>=36, zeroed), keeps 16B alignment
#define TOT (OFF + NN + 40)  // 1376 floats per node-array
#define KMAX 240             // Chebyshev iteration cap

// ---------------- 3x3 SAME conv, compile-time shapes, co-tile <=8 ------------
template<int CIN, int COUT, bool RELU>
__global__ __launch_bounds__(256) void conv_t(
    const float* __restrict__ in, const float* __restrict__ wgt,
    const float* __restrict__ bias, float* __restrict__ out)
{
  const int b   = blockIdx.z;
  const int co0 = blockIdx.y * 8;
  const int p   = blockIdx.x * 256 + threadIdx.x;
  if (p >= NN) return;
  const int py = p / 36, px = p % 36;

  // ci-invariant neighborhood offsets + masks
  int offs[9]; float msk[9];
#pragma unroll
  for (int dy = 0; dy < 3; ++dy)
#pragma unroll
    for (int dx = 0; dx < 3; ++dx) {
      const int yy = py + dy - 1, xx = px + dx - 1;
      const bool ok = ((unsigned)yy < 36u) && ((unsigned)xx < 36u);
      offs[dy * 3 + dx] = ok ? (yy * 36 + xx) : 0;
      msk[dy * 3 + dx]  = ok ? 1.f : 0.f;
    }

  constexpr int CT = (COUT < 8) ? COUT : 8;
  float acc[CT];
#pragma unroll
  for (int t = 0; t < CT; ++t) acc[t] = bias[co0 + t];

  const float* __restrict__ inp = in + (size_t)b * CIN * NN;
  const float* __restrict__ wB  = wgt + (size_t)co0 * CIN * 9;

#pragma unroll 8
  for (int ci = 0; ci < CIN; ++ci) {
    float v[9];
#pragma unroll
    for (int k9 = 0; k9 < 9; ++k9) v[k9] = msk[k9] * inp[ci * NN + offs[k9]];
#pragma unroll
    for (int t = 0; t < CT; ++t)
#pragma unroll
      for (int k9 = 0; k9 < 9; ++k9)
        acc[t] = fmaf(v[k9], wB[(t * CIN + ci) * 9 + k9], acc[t]);
  }
#pragma unroll
  for (int t = 0; t < CT; ++t) {
    float r = acc[t];
    if (RELU) r = fmaxf(r, 0.f);
    out[(size_t)(b * COUT + co0 + t) * NN + p] = r;
  }
}

// ------------- per-node edge weights: wh (to x+1), wv (to y+1) ---------------
__global__ __launch_bounds__(256) void edgew_k(const float* __restrict__ feat,
    float* __restrict__ wh, float* __restrict__ wv)
{
  const int b = blockIdx.y;
  const int n = blockIdx.x * 256 + threadIdx.x;
  if (n >= NN) return;
  const int col = n % 36, row = n / 36;
  float sh = 0.f, sv = 0.f;
#pragma unroll
  for (int f = 0; f < 6; ++f) {
    const float* __restrict__ fp = feat + (size_t)(b * 6 + f) * NN;
    const float a = fp[n];
    if (col < 35) { const float d = a - fp[n + 1];  sh += d * d; }
    if (row < 35) { const float d = a - fp[n + 36]; sv += d * d; }
  }
  wh[b * NN + n] = (col < 35) ? expf(-sh * 1e4f) : 0.f;
  wv[b * NN + n] = (row < 35) ? expf(-sv * 1e4f) : 0.f;
}

// ---- 9x { reweight -> adaptive Chebyshev solve of (I+uL)x = y } -------------
// One block per (b,c) system; 324 active threads own 4 row-aligned nodes each.
// Own d kept in registers; LDS only for halos (2x b128 + 2x b32 reads, 1x b128
// write per iter). Iteration count from Gershgorin bound: 2*rho_c^k <= 1e-5.
__global__ __launch_bounds__(384) void gtv_cheb_k(
    const float* __restrict__ xf, const float* __restrict__ up,
    const float* __restrict__ whg, const float* __restrict__ wvg,
    float* __restrict__ out)
{
  const int sys = blockIdx.x, b = sys / 3, ch = sys % 3;
  const int tid = threadIdx.x;
  const int wave = tid >> 6, lane = tid & 63;
  const bool act = tid < 324;
  const int qq = act ? tid : 0;
  const int i0 = OFF + 4 * qq;            // 16B-aligned LDS index

  __shared__ __align__(16) float ysL[TOT], ahL[TOT], avL[TOT], dA[TOT], dB[TOT];
  __shared__ float red[16];

  float u = up[0]; u = fminf(fmaxf(u, 0.001f), 1.0f);

  // zero pads (front OFF, back 40)
  if (tid < OFF) {
    const int t2 = OFF + NN + tid;
    ysL[tid] = 0.f; ahL[tid] = 0.f; avL[tid] = 0.f; dA[tid] = 0.f; dB[tid] = 0.f;
    ysL[t2] = 0.f; ahL[t2] = 0.f; avL[t2] = 0.f; dA[t2] = 0.f; dB[t2] = 0.f;
  }

  const float* __restrict__ xfB = xf + (size_t)(b * 3 + ch) * NN;
  float4 wh4 = make_float4(0.f, 0.f, 0.f, 0.f), wv4 = wh4;
  if (act) {
    *(float4*)&ysL[i0] = *(const float4*)&xfB[4 * qq];
    wh4 = *(const float4*)&whg[b * NN + 4 * qq];
    wv4 = *(const float4*)&wvg[b * NN + 4 * qq];
  }
  __syncthreads();

  float x[4] = {0.f, 0.f, 0.f, 0.f};

  for (int it = 0; it < 9; ++it) {
    // ---- P1: reweighted u-scaled edge coefficients from current y ----
    float4 yv = make_float4(0,0,0,0);
    float ah[4] = {0,0,0,0}, av[4] = {0,0,0,0};
    if (act) {
      yv = *(const float4*)&ysL[i0];
      const float yR = ysL[i0 + 4];
      const float4 yD = *(const float4*)&ysL[i0 + 36];
      ah[0] = u * wh4.x / fmaxf(fabsf(yv.x - yv.y), 0.01f);
      ah[1] = u * wh4.y / fmaxf(fabsf(yv.y - yv.z), 0.01f);
      ah[2] = u * wh4.z / fmaxf(fabsf(yv.z - yv.w), 0.01f);
      ah[3] = u * wh4.w / fmaxf(fabsf(yv.w - yR  ), 0.01f);
      av[0] = u * wv4.x / fmaxf(fabsf(yv.x - yD.x), 0.01f);
      av[1] = u * wv4.y / fmaxf(fabsf(yv.y - yD.y), 0.01f);
      av[2] = u * wv4.z / fmaxf(fabsf(yv.z - yD.z), 0.01f);
      av[3] = u * wv4.w / fmaxf(fabsf(yv.w - yD.w), 0.01f);
      *(float4*)&ahL[i0] = make_float4(ah[0], ah[1], ah[2], ah[3]);
      *(float4*)&avL[i0] = make_float4(av[0], av[1], av[2], av[3]);
    }
    __syncthreads();

    // ---- P2: stencil coeffs (regs), b -> dA, Gershgorin reduction ----
    float cL[4], cR[4], cU[4], cD[4], cc[4], bn[4];
    float mo = 0.f;
    if (act) {
      const float cl0 = ahL[i0 - 1];
      const float4 aU = *(const float4*)&avL[i0 - 36];
      cL[0] = cl0;  cL[1] = ah[0]; cL[2] = ah[1]; cL[3] = ah[2];
      cR[0] = ah[0]; cR[1] = ah[1]; cR[2] = ah[2]; cR[3] = ah[3];
      cU[0] = aU.x; cU[1] = aU.y; cU[2] = aU.z; cU[3] = aU.w;
      cD[0] = av[0]; cD[1] = av[1]; cD[2] = av[2]; cD[3] = av[3];
      bn[0] = yv.x; bn[1] = yv.y; bn[2] = yv.z; bn[3] = yv.w;
#pragma unroll
      for (int j = 0; j < 4; ++j) {
        const float offsum = cL[j] + cR[j] + cU[j] + cD[j];
        cc[j] = 1.f + offsum;
        mo = fmaxf(mo, offsum);
      }
      *(float4*)&dA[i0] = yv;
    } else {
#pragma unroll
      for (int j = 0; j < 4; ++j) { cL[j]=cR[j]=cU[j]=cD[j]=0.f; cc[j]=1.f; bn[j]=0.f; }
    }
#pragma unroll
    for (int o = 32; o >= 1; o >>= 1) mo = fmaxf(mo, __shfl_xor(mo, o));
    if (lane == 0) red[wave] = mo;
    __syncthreads();
    if (tid == 0) {
      float m = red[0];
      for (int w = 1; w < 6; ++w) m = fmaxf(m, red[w]);
      red[8] = m;
    }
    __syncthreads();

    const float maxoff = red[8];
    const float theta = 1.f + maxoff;
    const float del   = fmaxf(maxoff, 1e-30f);
    const float sig1  = theta / del;
    float rho = del / theta;

    // adaptive iteration count: 2*rho_c^k <= 1e-5
    const float kappa = 1.f + 2.f * maxoff;
    const float srk = sqrtf(kappa);
    const float rc  = (srk - 1.f) / (srk + 1.f);
    int kneed = (int)ceilf(12.21f / (-logf(rc)));   // rc==0 -> 0 -> clamped
    kneed = (kneed < 3) ? 3 : (kneed > KMAX ? KMAX : kneed);

    // ---- P3: x0 = b, r0 = b - A b, d0 = r0/theta -> dB ----
    float r[4], d[4];
    if (act) {
      const float dl = dA[i0 - 1], dr = dA[i0 + 4];
      const float4 u4 = *(const float4*)&dA[i0 - 36];
      const float4 d4 = *(const float4*)&dA[i0 + 36];
      const float uu[4] = {u4.x, u4.y, u4.z, u4.w};
      const float dd[4] = {d4.x, d4.y, d4.z, d4.w};
#pragma unroll
      for (int j = 0; j < 4; ++j) {
        const float nl = (j == 0) ? dl : bn[j - 1];
        const float nr = (j == 3) ? dr : bn[j + 1];
        const float Ab = cc[j] * bn[j] - cL[j] * nl - cR[j] * nr
                       - cU[j] * uu[j] - cD[j] * dd[j];
        x[j] = bn[j];
        r[j] = bn[j] - Ab;
        d[j] = r[j] / theta;
      }
      *(float4*)&dB[i0] = make_float4(d[0], d[1], d[2], d[3]);
    } else {
#pragma unroll
      for (int j = 0; j < 4; ++j) { r[j] = 0.f; d[j] = 0.f; }
    }
    __syncthreads();

    // ---- P4: Chebyshev 3-term recurrence, halo-only LDS traffic ----
    float* dc = dB; float* dnx = dA;
    for (int k = 0; k < kneed; ++k) {
      const float rn = 1.f / (2.f * sig1 - rho);
      const float cd = rn * rho, cr = 2.f * rn / del;
      rho = rn;
      if (act) {
        const float dl = dc[i0 - 1], dr = dc[i0 + 4];
        const float4 u4 = *(const float4*)&dc[i0 - 36];
        const float4 d4 = *(const float4*)&dc[i0 + 36];
        const float uu[4] = {u4.x, u4.y, u4.z, u4.w};
        const float dd[4] = {d4.x, d4.y, d4.z, d4.w};
        float dn[4];
#pragma unroll
        for (int j = 0; j < 4; ++j) {
          const float nl = (j == 0) ? dl : d[j - 1];
          const float nr = (j == 3) ? dr : d[j + 1];
          const float Ad = cc[j] * d[j] - cL[j] * nl - cR[j] * nr
                         - cU[j] * uu[j] - cD[j] * dd[j];
          x[j] += d[j];
          r[j] -= Ad;
          dn[j] = cd * d[j] + cr * r[j];
        }
        *(float4*)&dnx[i0] = make_float4(dn[0], dn[1], dn[2], dn[3]);
#pragma unroll
        for (int j = 0; j < 4; ++j) d[j] = dn[j];
      }
      __syncthreads();
      float* t = dc; dc = dnx; dnx = t;
    }

    // ---- commit x as next iteration's y ----
    if (act) *(float4*)&ysL[i0] = make_float4(x[0], x[1], x[2], x[3]);
    __syncthreads();
  }

  if (act) *(float4*)&out[(size_t)(b * 3 + ch) * NN + 4 * qq]
      = make_float4(x[0], x[1], x[2], x[3]);
}

// ----------------------------------------------------------------------------
extern "C" void kernel_launch(void* const* d_in, const int* in_sizes, int n_in,
                              void* d_out, int out_size, void* d_ws, size_t ws_size,
                              hipStream_t stream) {
  const float* xf     = (const float*)d_in[0];   // [2,3,36,36]
  const float* up     = (const float*)d_in[1];   // [1]
  const float* cw_in  = (const float*)d_in[3];   // [32,3,3,3]
  const float* b_in   = (const float*)d_in[4];   // [32]
  const float* cw_mid = (const float*)d_in[5];   // [5,32,32,3,3]
  const float* b_mid  = (const float*)d_in[6];   // [5,32]
  const float* cw_out = (const float*)d_in[7];   // [6,32,3,3]
  const float* b_out  = (const float*)d_in[8];   // [6]

  float* ws   = (float*)d_ws;
  float* wh   = ws;                   // 2592
  float* wv   = ws + 2592;            // 2592
  float* hb0  = ws + 5184;            // 82944
  float* hb1  = hb0 + 82944;          // 82944
  float* feat = hb1 + 82944;          // 15552

  const dim3 cgrid(6, 4, 2), cblk(256);
  conv_t<3, 32, true><<<cgrid, cblk, 0, stream>>>(xf, cw_in, b_in, hb0);
  const float* src = hb0; float* dst = hb1;
  for (int i = 0; i < 5; ++i) {
    conv_t<32, 32, true><<<cgrid, cblk, 0, stream>>>(src, cw_mid + i * 9216,
                                                     b_mid + i * 32, dst);
    const float* t = dst; dst = (float*)src; src = t;
  }
  conv_t<32, 6, false><<<dim3(6, 1, 2), cblk, 0, stream>>>(src, cw_out, b_out, feat);

  edgew_k<<<dim3(6, 2), cblk, 0, stream>>>(feat, wh, wv);

  gtv_cheb_k<<<dim3(6), dim3(384), 0, stream>>>(xf, up, wh, wv, (float*)d_out);
}

// Round 6
// 205.841 us; speedup vs baseline: 44.8204x; 1.2071x over previous
//
#include <hip/hip_runtime.h>
#include <math.h>

#define NN 1296              // 36*36 nodes
#define OFF 40               // front pad (>=36, zeroed), keeps 16B alignment
#define TOT (OFF + NN + 40)  // 1376 floats per node-array
#define KMAX 240             // Chebyshev iteration cap
#define PXW 21               // waves per (b,co) plane: ceil(1296/64)

// ------- 3x3 SAME conv, one thread per (pixel, co); co wave-uniform ----------
// Max-parallelism form: 2*COUT*21 waves. 288 independent L2 loads per thread
// (full MLP depth), scalar weight loads via readfirstlane'd co.
template<int CIN, int COUT, bool RELU>
__global__ __launch_bounds__(256) void conv_pc_t(
    const float* __restrict__ in, const float* __restrict__ wgt,
    const float* __restrict__ bias, float* __restrict__ out)
{
  const int gid  = blockIdx.x * 256 + threadIdx.x;
  const int wid  = gid >> 6, lane = gid & 63;
  const int px   = (wid % PXW) * 64 + lane;
  const int coV  = (wid / PXW) % COUT;
  const int bV   = wid / (PXW * COUT);
  const int co   = __builtin_amdgcn_readfirstlane(coV);   // wave-uniform
  const int b    = __builtin_amdgcn_readfirstlane(bV);
  if (px >= NN) return;

  const int py = px / 36, pxx = px % 36;
  int offs[9]; float msk[9];
#pragma unroll
  for (int dy = 0; dy < 3; ++dy)
#pragma unroll
    for (int dx = 0; dx < 3; ++dx) {
      const int yy = py + dy - 1, xx = pxx + dx - 1;
      const bool ok = ((unsigned)yy < 36u) && ((unsigned)xx < 36u);
      offs[dy * 3 + dx] = ok ? (yy * 36 + xx) : 0;
      msk[dy * 3 + dx]  = ok ? 1.f : 0.f;
    }

  float acc = bias[co];
  const float* __restrict__ inp = in + (size_t)b * CIN * NN;
  const float* __restrict__ wB  = wgt + (size_t)co * CIN * 9;

#pragma unroll 8
  for (int ci = 0; ci < CIN; ++ci) {
    float v[9];
#pragma unroll
    for (int k9 = 0; k9 < 9; ++k9) v[k9] = msk[k9] * inp[ci * NN + offs[k9]];
#pragma unroll
    for (int k9 = 0; k9 < 9; ++k9) acc = fmaf(v[k9], wB[ci * 9 + k9], acc);
  }
  if (RELU) acc = fmaxf(acc, 0.f);
  out[(size_t)(b * COUT + co) * NN + px] = acc;
}

// ------------- per-node edge weights: wh (to x+1), wv (to y+1) ---------------
__global__ __launch_bounds__(256) void edgew_k(const float* __restrict__ feat,
    float* __restrict__ wh, float* __restrict__ wv)
{
  const int b = blockIdx.y;
  const int n = blockIdx.x * 256 + threadIdx.x;
  if (n >= NN) return;
  const int col = n % 36, row = n / 36;
  float sh = 0.f, sv = 0.f;
#pragma unroll
  for (int f = 0; f < 6; ++f) {
    const float* __restrict__ fp = feat + (size_t)(b * 6 + f) * NN;
    const float a = fp[n];
    if (col < 35) { const float d = a - fp[n + 1];  sh += d * d; }
    if (row < 35) { const float d = a - fp[n + 36]; sv += d * d; }
  }
  wh[b * NN + n] = (col < 35) ? expf(-sh * 1e4f) : 0.f;
  wv[b * NN + n] = (row < 35) ? expf(-sv * 1e4f) : 0.f;
}

// ---- 9x { reweight -> adaptive Chebyshev solve of (I+uL)x = y } -------------
// One block per (b,c) system; 324 active threads own 4 row-aligned nodes each.
// Iteration count from Gershgorin bound: 2*rho_c^k <= ~7e-4 (measured: final
// error contracts ~6x below per-solve bound; >15x margin vs 7.2e-2 threshold).
__global__ __launch_bounds__(384) void gtv_cheb_k(
    const float* __restrict__ xf, const float* __restrict__ up,
    const float* __restrict__ whg, const float* __restrict__ wvg,
    float* __restrict__ out)
{
  const int sys = blockIdx.x, b = sys / 3, ch = sys % 3;
  const int tid = threadIdx.x;
  const int wave = tid >> 6, lane = tid & 63;
  const bool act = tid < 324;
  const int qq = act ? tid : 0;
  const int i0 = OFF + 4 * qq;            // 16B-aligned LDS index

  __shared__ __align__(16) float ysL[TOT], ahL[TOT], avL[TOT], dA[TOT], dB[TOT];
  __shared__ float red[16];

  float u = up[0]; u = fminf(fmaxf(u, 0.001f), 1.0f);

  if (tid < OFF) {
    const int t2 = OFF + NN + tid;
    ysL[tid] = 0.f; ahL[tid] = 0.f; avL[tid] = 0.f; dA[tid] = 0.f; dB[tid] = 0.f;
    ysL[t2] = 0.f; ahL[t2] = 0.f; avL[t2] = 0.f; dA[t2] = 0.f; dB[t2] = 0.f;
  }

  const float* __restrict__ xfB = xf + (size_t)(b * 3 + ch) * NN;
  float4 wh4 = make_float4(0.f, 0.f, 0.f, 0.f), wv4 = wh4;
  if (act) {
    *(float4*)&ysL[i0] = *(const float4*)&xfB[4 * qq];
    wh4 = *(const float4*)&whg[b * NN + 4 * qq];
    wv4 = *(const float4*)&wvg[b * NN + 4 * qq];
  }
  __syncthreads();

  float x[4] = {0.f, 0.f, 0.f, 0.f};

  for (int it = 0; it < 9; ++it) {
    // ---- P1: reweighted u-scaled edge coefficients from current y ----
    float4 yv = make_float4(0,0,0,0);
    float ah[4] = {0,0,0,0}, av[4] = {0,0,0,0};
    if (act) {
      yv = *(const float4*)&ysL[i0];
      const float yR = ysL[i0 + 4];
      const float4 yD = *(const float4*)&ysL[i0 + 36];
      ah[0] = u * wh4.x / fmaxf(fabsf(yv.x - yv.y), 0.01f);
      ah[1] = u * wh4.y / fmaxf(fabsf(yv.y - yv.z), 0.01f);
      ah[2] = u * wh4.z / fmaxf(fabsf(yv.z - yv.w), 0.01f);
      ah[3] = u * wh4.w / fmaxf(fabsf(yv.w - yR  ), 0.01f);
      av[0] = u * wv4.x / fmaxf(fabsf(yv.x - yD.x), 0.01f);
      av[1] = u * wv4.y / fmaxf(fabsf(yv.y - yD.y), 0.01f);
      av[2] = u * wv4.z / fmaxf(fabsf(yv.z - yD.z), 0.01f);
      av[3] = u * wv4.w / fmaxf(fabsf(yv.w - yD.w), 0.01f);
      *(float4*)&ahL[i0] = make_float4(ah[0], ah[1], ah[2], ah[3]);
      *(float4*)&avL[i0] = make_float4(av[0], av[1], av[2], av[3]);
    }
    __syncthreads();

    // ---- P2: stencil coeffs (regs), b -> dA, Gershgorin reduction ----
    float cL[4], cR[4], cU[4], cD[4], cc[4], bn[4];
    float mo = 0.f;
    if (act) {
      const float cl0 = ahL[i0 - 1];
      const float4 aU = *(const float4*)&avL[i0 - 36];
      cL[0] = cl0;  cL[1] = ah[0]; cL[2] = ah[1]; cL[3] = ah[2];
      cR[0] = ah[0]; cR[1] = ah[1]; cR[2] = ah[2]; cR[3] = ah[3];
      cU[0] = aU.x; cU[1] = aU.y; cU[2] = aU.z; cU[3] = aU.w;
      cD[0] = av[0]; cD[1] = av[1]; cD[2] = av[2]; cD[3] = av[3];
      bn[0] = yv.x; bn[1] = yv.y; bn[2] = yv.z; bn[3] = yv.w;
#pragma unroll
      for (int j = 0; j < 4; ++j) {
        const float offsum = cL[j] + cR[j] + cU[j] + cD[j];
        cc[j] = 1.f + offsum;
        mo = fmaxf(mo, offsum);
      }
      *(float4*)&dA[i0] = yv;
    } else {
#pragma unroll
      for (int j = 0; j < 4; ++j) { cL[j]=cR[j]=cU[j]=cD[j]=0.f; cc[j]=1.f; bn[j]=0.f; }
    }
#pragma unroll
    for (int o = 32; o >= 1; o >>= 1) mo = fmaxf(mo, __shfl_xor(mo, o));
    if (lane == 0) red[wave] = mo;
    __syncthreads();
    if (tid == 0) {
      float m = red[0];
      for (int w = 1; w < 6; ++w) m = fmaxf(m, red[w]);
      red[8] = m;
    }
    __syncthreads();

    const float maxoff = red[8];
    const float theta = 1.f + maxoff;
    const float del   = fmaxf(maxoff, 1e-30f);
    const float sig1  = theta / del;
    float rho = del / theta;

    // adaptive iteration count: 2*rho_c^k <= ~7e-4
    const float kappa = 1.f + 2.f * maxoff;
    const float srk = sqrtf(kappa);
    const float rc  = (srk - 1.f) / (srk + 1.f);
    int kneed = (int)ceilf(8.0f / (-logf(rc)));
    kneed = (kneed < 3) ? 3 : (kneed > KMAX ? KMAX : kneed);

    // ---- P3: x0 = b, r0 = b - A b, d0 = r0/theta -> dB ----
    float r[4], d[4];
    if (act) {
      const float dl = dA[i0 - 1], dr = dA[i0 + 4];
      const float4 u4 = *(const float4*)&dA[i0 - 36];
      const float4 d4 = *(const float4*)&dA[i0 + 36];
      const float uu[4] = {u4.x, u4.y, u4.z, u4.w};
      const float dd[4] = {d4.x, d4.y, d4.z, d4.w};
#pragma unroll
      for (int j = 0; j < 4; ++j) {
        const float nl = (j == 0) ? dl : bn[j - 1];
        const float nr = (j == 3) ? dr : bn[j + 1];
        const float Ab = cc[j] * bn[j] - cL[j] * nl - cR[j] * nr
                       - cU[j] * uu[j] - cD[j] * dd[j];
        x[j] = bn[j];
        r[j] = bn[j] - Ab;
        d[j] = r[j] / theta;
      }
      *(float4*)&dB[i0] = make_float4(d[0], d[1], d[2], d[3]);
    } else {
#pragma unroll
      for (int j = 0; j < 4; ++j) { r[j] = 0.f; d[j] = 0.f; }
    }
    __syncthreads();

    // ---- P4: Chebyshev 3-term recurrence, halo-only LDS traffic ----
    float* dc = dB; float* dnx = dA;
    for (int k = 0; k < kneed; ++k) {
      const float rn = 1.f / (2.f * sig1 - rho);
      const float cd = rn * rho, cr = 2.f * rn / del;
      rho = rn;
      if (act) {
        const float dl = dc[i0 - 1], dr = dc[i0 + 4];
        const float4 u4 = *(const float4*)&dc[i0 - 36];
        const float4 d4 = *(const float4*)&dc[i0 + 36];
        const float uu[4] = {u4.x, u4.y, u4.z, u4.w};
        const float dd[4] = {d4.x, d4.y, d4.z, d4.w};
        float dn[4];
#pragma unroll
        for (int j = 0; j < 4; ++j) {
          const float nl = (j == 0) ? dl : d[j - 1];
          const float nr = (j == 3) ? dr : d[j + 1];
          const float Ad = cc[j] * d[j] - cL[j] * nl - cR[j] * nr
                         - cU[j] * uu[j] - cD[j] * dd[j];
          x[j] += d[j];
          r[j] -= Ad;
          dn[j] = cd * d[j] + cr * r[j];
        }
        *(float4*)&dnx[i0] = make_float4(dn[0], dn[1], dn[2], dn[3]);
#pragma unroll
        for (int j = 0; j < 4; ++j) d[j] = dn[j];
      }
      __syncthreads();
      float* t = dc; dc = dnx; dnx = t;
    }

    // ---- commit x as next iteration's y ----
    if (act) *(float4*)&ysL[i0] = make_float4(x[0], x[1], x[2], x[3]);
    __syncthreads();
  }

  if (act) *(float4*)&out[(size_t)(b * 3 + ch) * NN + 4 * qq]
      = make_float4(x[0], x[1], x[2], x[3]);
}

// ----------------------------------------------------------------------------
extern "C" void kernel_launch(void* const* d_in, const int* in_sizes, int n_in,
                              void* d_out, int out_size, void* d_ws, size_t ws_size,
                              hipStream_t stream) {
  const float* xf     = (const float*)d_in[0];   // [2,3,36,36]
  const float* up     = (const float*)d_in[1];   // [1]
  const float* cw_in  = (const float*)d_in[3];   // [32,3,3,3]
  const float* b_in   = (const float*)d_in[4];   // [32]
  const float* cw_mid = (const float*)d_in[5];   // [5,32,32,3,3]
  const float* b_mid  = (const float*)d_in[6];   // [5,32]
  const float* cw_out = (const float*)d_in[7];   // [6,32,3,3]
  const float* b_out  = (const float*)d_in[8];   // [6]

  float* ws   = (float*)d_ws;
  float* wh   = ws;                   // 2592
  float* wv   = ws + 2592;            // 2592
  float* hb0  = ws + 5184;            // 82944
  float* hb1  = hb0 + 82944;          // 82944
  float* feat = hb1 + 82944;          // 15552

  const int blk32 = (2 * 32 * PXW) / 4;    // 336 blocks (1344 waves)
  const int blk6  = (2 * 6 * PXW + 3) / 4; // 63 blocks
  conv_pc_t<3, 32, true><<<dim3(blk32), dim3(256), 0, stream>>>(xf, cw_in, b_in, hb0);
  const float* src = hb0; float* dst = hb1;
  for (int i = 0; i < 5; ++i) {
    conv_pc_t<32, 32, true><<<dim3(blk32), dim3(256), 0, stream>>>(
        src, cw_mid + i * 9216, b_mid + i * 32, dst);
    const float* t = dst; dst = (float*)src; src = t;
  }
  conv_pc_t<32, 6, false><<<dim3(blk6), dim3(256), 0, stream>>>(src, cw_out, b_out, feat);

  edgew_k<<<dim3(6, 2), dim3(256), 0, stream>>>(feat, wh, wv);

  gtv_cheb_k<<<dim3(6), dim3(384), 0, stream>>>(xf, up, wh, wv, (float*)d_out);
}